// Round 1
// baseline (390.319 us; speedup 1.0000x reference)
//
#include <hip/hip_runtime.h>
#include <cfloat>
#include <math.h>

#define IMG_B 16
#define IMG_H 1024
#define IMG_W 1280
#define NPIX (IMG_H * IMG_W)          // 1,310,720
#define BINS 256
#define ROWS_PER_BLOCK 16
#define BLOCKS_PER_IMG_P1 (IMG_H / ROWS_PER_BLOCK)   // 64
#define T1 (IMG_W / 4)                 // 320 threads, one float4 per thread per row
#define BPI2 64                        // blocks per image, pass2

// ---------- helpers ----------
__device__ __forceinline__ unsigned encf(float f) {
    unsigned u = __float_as_uint(f);
    return (u >> 31) ? ~u : (u | 0x80000000u);
}
__device__ __forceinline__ float decf(unsigned u) {
    unsigned b = (u & 0x80000000u) ? (u & 0x7fffffffu) : ~u;
    return __uint_as_float(b);
}

// ws layout (bytes):
//   sums   : double[IMG_B*4]   @ 0      (sum, sumsq, lapsum, lapsumsq)
//   mm     : unsigned[IMG_B*2] @ 512    (encoded min, encoded max)
//   hist   : float[IMG_B*256]  @ 640
//   featsw : float[IMG_B*5]    @ 640+16384

__global__ __launch_bounds__(256) void k_init(double* sums, unsigned* mm, float* hist) {
    int t = blockIdx.x * 256 + threadIdx.x;   // grid 16x256 = 4096
    if (t < IMG_B * 4) sums[t] = 0.0;
    if (t < IMG_B) { mm[2 * t] = 0xFFFFFFFFu; mm[2 * t + 1] = 0u; }
    if (t < IMG_B * BINS) hist[t] = 0.0f;
}

__global__ __launch_bounds__(T1) void k_pass1(const float* __restrict__ img,
                                              double* __restrict__ sums,
                                              unsigned* __restrict__ mm) {
    int blk = blockIdx.x;                       // 0..1023
    int b   = blk >> 6;                         // image
    int r0  = (blk & 63) * ROWS_PER_BLOCK;
    const float* base = img + (size_t)b * NPIX;
    int c = threadIdx.x;                        // float4 column 0..319

    float fmn = FLT_MAX, fmx = -FLT_MAX;
    double s = 0.0, s2 = 0.0, ls = 0.0, ls2 = 0.0;

    for (int i = 0; i < ROWS_PER_BLOCK; ++i) {
        int r = r0 + i;
        const float* rowf = base + (size_t)r * IMG_W;
        float4 m = ((const float4*)rowf)[c];
        float4 up = make_float4(0.f, 0.f, 0.f, 0.f);
        float4 dn = make_float4(0.f, 0.f, 0.f, 0.f);
        if (r > 0)          up = ((const float4*)(rowf - IMG_W))[c];
        if (r < IMG_H - 1)  dn = ((const float4*)(rowf + IMG_W))[c];
        float lft = (c > 0)      ? rowf[4 * c - 1] : 0.f;
        float rgt = (c < T1 - 1) ? rowf[4 * c + 4] : 0.f;

        fmn = fminf(fmn, fminf(fminf(m.x, m.y), fminf(m.z, m.w)));
        fmx = fmaxf(fmx, fmaxf(fmaxf(m.x, m.y), fmaxf(m.z, m.w)));
        s  += (double)m.x + (double)m.y + (double)m.z + (double)m.w;
        s2 += (double)m.x * m.x + (double)m.y * m.y + (double)m.z * m.z + (double)m.w * m.w;

        float l0 = up.x + dn.x + lft + m.y - 4.f * m.x;
        float l1 = up.y + dn.y + m.x + m.z - 4.f * m.y;
        float l2 = up.z + dn.z + m.y + m.w - 4.f * m.z;
        float l3 = up.w + dn.w + m.z + rgt - 4.f * m.w;
        ls  += (double)l0 + (double)l1 + (double)l2 + (double)l3;
        ls2 += (double)l0 * l0 + (double)l1 * l1 + (double)l2 * l2 + (double)l3 * l3;
    }

    // wave (64) reduce
    for (int o = 32; o; o >>= 1) {
        s   += __shfl_down(s,   (unsigned)o, 64);
        s2  += __shfl_down(s2,  (unsigned)o, 64);
        ls  += __shfl_down(ls,  (unsigned)o, 64);
        ls2 += __shfl_down(ls2, (unsigned)o, 64);
        fmn = fminf(fmn, __shfl_down(fmn, (unsigned)o, 64));
        fmx = fmaxf(fmx, __shfl_down(fmx, (unsigned)o, 64));
    }
    __shared__ double rd[4][5];
    __shared__ float  rf[2][5];
    int lane = threadIdx.x & 63, wv = threadIdx.x >> 6;   // 5 waves
    if (lane == 0) {
        rd[0][wv] = s; rd[1][wv] = s2; rd[2][wv] = ls; rd[3][wv] = ls2;
        rf[0][wv] = fmn; rf[1][wv] = fmx;
    }
    __syncthreads();
    if (threadIdx.x == 0) {
        double S = 0, S2 = 0, LS = 0, LS2 = 0;
        float mn = FLT_MAX, mx = -FLT_MAX;
        for (int i = 0; i < 5; ++i) {
            S += rd[0][i]; S2 += rd[1][i]; LS += rd[2][i]; LS2 += rd[3][i];
            mn = fminf(mn, rf[0][i]); mx = fmaxf(mx, rf[1][i]);
        }
        atomicAdd(&sums[b * 4 + 0], S);
        atomicAdd(&sums[b * 4 + 1], S2);
        atomicAdd(&sums[b * 4 + 2], LS);
        atomicAdd(&sums[b * 4 + 3], LS2);
        atomicMin(&mm[b * 2 + 0], encf(mn));
        atomicMax(&mm[b * 2 + 1], encf(mx));
    }
}

__global__ __launch_bounds__(256) void k_pass2(const float* __restrict__ img,
                                               const unsigned* __restrict__ mm,
                                               float* __restrict__ hist) {
    __shared__ float lh[BINS];
    int b     = blockIdx.x / BPI2;
    int blkin = blockIdx.x % BPI2;
    lh[threadIdx.x] = 0.f;
    __syncthreads();

    float fmn = decf(mm[b * 2 + 0]);
    float fmx = decf(mm[b * 2 + 1]);
    float rng = fmx - fmn;
    if (rng == 0.f) rng = 1.f;
    float inv = 1.f / rng;

    const float4* p = (const float4*)(img + (size_t)b * NPIX);
    int nf4 = NPIX / 4;   // 327680
    for (int i = blkin * 256 + threadIdx.x; i < nf4; i += BPI2 * 256) {
        float4 v = p[i];
        #pragma unroll
        for (int j = 0; j < 4; ++j) {
            float vv = (j == 0) ? v.x : (j == 1) ? v.y : (j == 2) ? v.z : v.w;
            float x  = fminf(fmaxf((vv - fmn) * inv, 0.f), 1.f);
            float pp = x * 256.f - 0.5f;
            float fi = floorf(pp);
            int   i0 = (int)fi;
            float w1 = pp - fi;
            if (i0 >= 0)       atomicAdd(&lh[i0], 1.f - w1);
            if (i0 < BINS - 1) atomicAdd(&lh[i0 + 1], w1);
        }
    }
    __syncthreads();
    float hv = lh[threadIdx.x];
    if (hv != 0.f) atomicAdd(&hist[b * BINS + threadIdx.x], hv);
}

__global__ __launch_bounds__(256) void k_pass3(const float* __restrict__ hist,
                                               const double* __restrict__ sums,
                                               const unsigned* __restrict__ mm,
                                               float* __restrict__ featsw,
                                               float* __restrict__ out) {
    int b = blockIdx.x, t = threadIdx.x;
    float h = hist[b * BINS + t];

    __shared__ float red[4], red2[4];
    float tot = h;
    for (int o = 32; o; o >>= 1) tot += __shfl_down(tot, (unsigned)o, 64);
    if ((t & 63) == 0) red[t >> 6] = tot;
    __syncthreads();
    tot = red[0] + red[1] + red[2] + red[3];

    float hn = h / (tot + 1e-10f);
    float ce = hn * log2f(hn + 1e-10f);
    for (int o = 32; o; o >>= 1) ce += __shfl_down(ce, (unsigned)o, 64);
    if ((t & 63) == 0) red2[t >> 6] = ce;
    __syncthreads();

    if (t == 0) {
        float ent = -(red2[0] + red2[1] + red2[2] + red2[3]) / 8.f;  // /log2(256)
        float gmax = -FLT_MAX;
        for (int i = 0; i < IMG_B; ++i) gmax = fmaxf(gmax, decf(mm[i * 2 + 1]));
        float sc = (gmax > 1.f) ? (1.f / 16383.f) : 1.f;
        double N = (double)NPIX;
        double S = sums[b * 4 + 0], S2 = sums[b * 4 + 1];
        double LS = sums[b * 4 + 2], LS2 = sums[b * 4 + 3];
        double sc2 = (double)sc * (double)sc;
        float var  = (float)((S2  - S  * S  / N) / (N - 1.0) * sc2);
        float lvar = (float)((LS2 - LS * LS / N) / (N - 1.0) * sc2);
        float mn = decf(mm[b * 2 + 0]) * sc;
        float mx = decf(mm[b * 2 + 1]) * sc;
        float* fo = out + 16 + 48 + b * 5;  // feats region
        fo[0] = var; fo[1] = mn; fo[2] = mx; fo[3] = ent; fo[4] = lvar;
        float* fw = featsw + b * 5;
        fw[0] = var; fw[1] = mn; fw[2] = mx; fw[3] = ent; fw[4] = lvar;
    }
}

__global__ __launch_bounds__(64) void k_pass4(const float* __restrict__ feats,
                                              const float* __restrict__ W1, const float* __restrict__ b1,
                                              const float* __restrict__ W2, const float* __restrict__ b2,
                                              const float* __restrict__ W3, const float* __restrict__ b3,
                                              float* __restrict__ out) {
    int t = threadIdx.x;
    __shared__ float f[5], h1[64], h2[64], lg[3];
    for (int b = 0; b < IMG_B; ++b) {
        if (t < 5) f[t] = feats[b * 5 + t];
        __syncthreads();
        float a = b1[t];
        #pragma unroll
        for (int k = 0; k < 5; ++k) a += W1[t * 5 + k] * f[k];
        h1[t] = fmaxf(a, 0.f);
        __syncthreads();
        float a2 = b2[t];
        #pragma unroll
        for (int k = 0; k < 64; ++k) a2 += W2[t * 64 + k] * h1[k];
        h2[t] = fmaxf(a2, 0.f);
        __syncthreads();
        if (t < 3) {
            float a3 = b3[t];
            #pragma unroll
            for (int k = 0; k < 64; ++k) a3 += W3[t * 64 + k] * h2[k];
            lg[t] = a3;
        }
        __syncthreads();
        if (t == 0) {
            float m = fmaxf(lg[0], fmaxf(lg[1], lg[2]));
            float e0 = expf(lg[0] - m), e1 = expf(lg[1] - m), e2 = expf(lg[2] - m);
            float inv = 1.f / (e0 + e1 + e2);
            float p0 = e0 * inv, p1 = e1 * inv, p2 = e2 * inv;
            out[16 + b * 3 + 0] = p0;
            out[16 + b * 3 + 1] = p1;
            out[16 + b * 3 + 2] = p2;
            int cid = 0; float bm = p0;
            if (p1 > bm) { bm = p1; cid = 1; }
            if (p2 > bm) { bm = p2; cid = 2; }
            out[b] = (float)cid;
        }
        __syncthreads();
    }
}

extern "C" void kernel_launch(void* const* d_in, const int* in_sizes, int n_in,
                              void* d_out, int out_size, void* d_ws, size_t ws_size,
                              hipStream_t stream) {
    const float* img = (const float*)d_in[0];
    const float* W1  = (const float*)d_in[1];
    const float* b1  = (const float*)d_in[2];
    const float* W2  = (const float*)d_in[3];
    const float* b2  = (const float*)d_in[4];
    const float* W3  = (const float*)d_in[5];
    const float* b3  = (const float*)d_in[6];
    float* out = (float*)d_out;

    char* ws = (char*)d_ws;
    double*   sums   = (double*)ws;                         // 16*4 doubles
    unsigned* mm     = (unsigned*)(ws + 512);               // 16*2 uints
    float*    hist   = (float*)(ws + 640);                  // 16*256 floats
    float*    featsw = (float*)(ws + 640 + IMG_B * BINS * 4);

    k_init <<<16, 256, 0, stream>>>(sums, mm, hist);
    k_pass1<<<IMG_B * BLOCKS_PER_IMG_P1, T1, 0, stream>>>(img, sums, mm);
    k_pass2<<<IMG_B * BPI2, 256, 0, stream>>>(img, mm, hist);
    k_pass3<<<IMG_B, 256, 0, stream>>>(hist, sums, mm, featsw, out);
    k_pass4<<<1, 64, 0, stream>>>(featsw, W1, b1, W2, b2, W3, b3, out);
}

// Round 2
// 175.052 us; speedup vs baseline: 2.2297x; 2.2297x over previous
//
#include <hip/hip_runtime.h>
#include <cfloat>
#include <math.h>

#define IMG_B 16
#define IMG_H 1024
#define IMG_W 1280
#define NPIX (IMG_H * IMG_W)          // 1,310,720
#define BINS 256
#define ROWS_PER_BLOCK 16
#define BLOCKS_PER_IMG_P1 (IMG_H / ROWS_PER_BLOCK)   // 64
#define T1 (IMG_W / 4)                 // 320 threads, one float4 per thread per row
#define BPI2 64                        // blocks per image, pass2
#define FIXP 65536.0f                  // fixed-point weight scale (2^16)

// ---------- helpers ----------
__device__ __forceinline__ unsigned encf(float f) {
    unsigned u = __float_as_uint(f);
    return (u >> 31) ? ~u : (u | 0x80000000u);
}
__device__ __forceinline__ float decf(unsigned u) {
    unsigned b = (u & 0x80000000u) ? (u & 0x7fffffffu) : ~u;
    return __uint_as_float(b);
}

// ws layout (bytes):
//   partials : double[1024*4]           @ 0        (sum,sumsq,lapsum,lapsumsq per pass1 block)
//   mm       : unsigned[IMG_B*2]        @ 32768    (encoded min, encoded max)
//   hist64   : unsigned long long[16*256] @ 32896  (per-image fixed-point histogram)
//   featsw   : float[IMG_B*5]           @ 65664

__global__ __launch_bounds__(256) void k_init(unsigned* mm, unsigned long long* hist64) {
    int t = blockIdx.x * 256 + threadIdx.x;   // grid 16x256 = 4096
    hist64[t] = 0ull;                          // exactly 16*256 entries
    if (t < IMG_B) { mm[2 * t] = 0xFFFFFFFFu; mm[2 * t + 1] = 0u; }
}

__global__ __launch_bounds__(T1) void k_pass1(const float* __restrict__ img,
                                              double* __restrict__ partials,
                                              unsigned* __restrict__ mm) {
    int blk = blockIdx.x;                       // 0..1023
    int b   = blk >> 6;                         // image
    int r0  = (blk & 63) * ROWS_PER_BLOCK;
    const float* base = img + (size_t)b * NPIX;
    int c = threadIdx.x;                        // float4 column 0..319

    float fmn = FLT_MAX, fmx = -FLT_MAX;
    double s = 0.0, s2 = 0.0, ls = 0.0, ls2 = 0.0;

    for (int i = 0; i < ROWS_PER_BLOCK; ++i) {
        int r = r0 + i;
        const float* rowf = base + (size_t)r * IMG_W;
        float4 m = ((const float4*)rowf)[c];
        float4 up = make_float4(0.f, 0.f, 0.f, 0.f);
        float4 dn = make_float4(0.f, 0.f, 0.f, 0.f);
        if (r > 0)          up = ((const float4*)(rowf - IMG_W))[c];
        if (r < IMG_H - 1)  dn = ((const float4*)(rowf + IMG_W))[c];
        float lft = (c > 0)      ? rowf[4 * c - 1] : 0.f;
        float rgt = (c < T1 - 1) ? rowf[4 * c + 4] : 0.f;

        fmn = fminf(fmn, fminf(fminf(m.x, m.y), fminf(m.z, m.w)));
        fmx = fmaxf(fmx, fmaxf(fmaxf(m.x, m.y), fmaxf(m.z, m.w)));
        s  += (double)m.x + (double)m.y + (double)m.z + (double)m.w;
        s2 += (double)m.x * m.x + (double)m.y * m.y + (double)m.z * m.z + (double)m.w * m.w;

        float l0 = up.x + dn.x + lft + m.y - 4.f * m.x;
        float l1 = up.y + dn.y + m.x + m.z - 4.f * m.y;
        float l2 = up.z + dn.z + m.y + m.w - 4.f * m.z;
        float l3 = up.w + dn.w + m.z + rgt - 4.f * m.w;
        ls  += (double)l0 + (double)l1 + (double)l2 + (double)l3;
        ls2 += (double)l0 * l0 + (double)l1 * l1 + (double)l2 * l2 + (double)l3 * l3;
    }

    // wave (64) reduce
    for (int o = 32; o; o >>= 1) {
        s   += __shfl_down(s,   (unsigned)o, 64);
        s2  += __shfl_down(s2,  (unsigned)o, 64);
        ls  += __shfl_down(ls,  (unsigned)o, 64);
        ls2 += __shfl_down(ls2, (unsigned)o, 64);
        fmn = fminf(fmn, __shfl_down(fmn, (unsigned)o, 64));
        fmx = fmaxf(fmx, __shfl_down(fmx, (unsigned)o, 64));
    }
    __shared__ double rd[4][5];
    __shared__ float  rf[2][5];
    int lane = threadIdx.x & 63, wv = threadIdx.x >> 6;   // 5 waves
    if (lane == 0) {
        rd[0][wv] = s; rd[1][wv] = s2; rd[2][wv] = ls; rd[3][wv] = ls2;
        rf[0][wv] = fmn; rf[1][wv] = fmx;
    }
    __syncthreads();
    if (threadIdx.x == 0) {
        double S = 0, S2 = 0, LS = 0, LS2 = 0;
        float mn = FLT_MAX, mx = -FLT_MAX;
        for (int i = 0; i < 5; ++i) {
            S += rd[0][i]; S2 += rd[1][i]; LS += rd[2][i]; LS2 += rd[3][i];
            mn = fminf(mn, rf[0][i]); mx = fmaxf(mx, rf[1][i]);
        }
        double* p = partials + (size_t)blk * 4;
        p[0] = S; p[1] = S2; p[2] = LS; p[3] = LS2;        // contention-free
        atomicMin(&mm[b * 2 + 0], encf(mn));               // native u32 atomic
        atomicMax(&mm[b * 2 + 1], encf(mx));
    }
}

__global__ __launch_bounds__(256) void k_pass2(const float* __restrict__ img,
                                               const unsigned* __restrict__ mm,
                                               unsigned long long* __restrict__ hist64) {
    __shared__ unsigned lh[BINS];
    int b     = blockIdx.x / BPI2;
    int blkin = blockIdx.x % BPI2;
    lh[threadIdx.x] = 0u;
    __syncthreads();

    float fmn = decf(mm[b * 2 + 0]);
    float fmx = decf(mm[b * 2 + 1]);
    float rng = fmx - fmn;
    if (rng == 0.f) rng = 1.f;
    float inv = 1.f / rng;

    const float4* p = (const float4*)(img + (size_t)b * NPIX);
    int nf4 = NPIX / 4;   // 327680
    for (int i = blkin * 256 + threadIdx.x; i < nf4; i += BPI2 * 256) {
        float4 v = p[i];
        #pragma unroll
        for (int j = 0; j < 4; ++j) {
            float vv = (j == 0) ? v.x : (j == 1) ? v.y : (j == 2) ? v.z : v.w;
            float x  = fminf(fmaxf((vv - fmn) * inv, 0.f), 1.f);
            float pp = x * 256.f - 0.5f;
            float fi = floorf(pp);
            int   i0 = (int)fi;
            float w1 = pp - fi;
            unsigned w1q = (unsigned)(w1 * FIXP + 0.5f);
            unsigned w0q = 65536u - w1q;
            if (i0 >= 0)       atomicAdd(&lh[i0], w0q);        // native ds_add_u32
            if (i0 < BINS - 1) atomicAdd(&lh[i0 + 1], w1q);
        }
    }
    __syncthreads();
    unsigned hv = lh[threadIdx.x];
    if (hv != 0u)
        atomicAdd(&hist64[b * BINS + threadIdx.x], (unsigned long long)hv);  // native u64
}

__global__ __launch_bounds__(256) void k_pass3(const unsigned long long* __restrict__ hist64,
                                               const double* __restrict__ partials,
                                               const unsigned* __restrict__ mm,
                                               float* __restrict__ featsw,
                                               float* __restrict__ out) {
    int b = blockIdx.x, t = threadIdx.x;
    double h = (double)hist64[b * BINS + t] * (1.0 / 65536.0);

    __shared__ double red[4];
    __shared__ float red2[4];
    __shared__ double mom[4];
    double tot = h;
    for (int o = 32; o; o >>= 1) tot += __shfl_down(tot, (unsigned)o, 64);
    if ((t & 63) == 0) red[t >> 6] = tot;

    // wave 0 concurrently reduces the pass1 moment partials (64 blocks/image)
    if (t < 64) {
        const double* p = partials + ((size_t)b * 64 + t) * 4;
        double q0 = p[0], q1 = p[1], q2 = p[2], q3 = p[3];
        for (int o = 32; o; o >>= 1) {
            q0 += __shfl_down(q0, (unsigned)o, 64);
            q1 += __shfl_down(q1, (unsigned)o, 64);
            q2 += __shfl_down(q2, (unsigned)o, 64);
            q3 += __shfl_down(q3, (unsigned)o, 64);
        }
        if (t == 0) { mom[0] = q0; mom[1] = q1; mom[2] = q2; mom[3] = q3; }
    }
    __syncthreads();
    double tot_all = red[0] + red[1] + red[2] + red[3];

    float hn = (float)(h / (tot_all + 1e-10));
    float ce = hn * log2f(hn + 1e-10f);
    for (int o = 32; o; o >>= 1) ce += __shfl_down(ce, (unsigned)o, 64);
    if ((t & 63) == 0) red2[t >> 6] = ce;
    __syncthreads();

    if (t == 0) {
        float ent = -(red2[0] + red2[1] + red2[2] + red2[3]) / 8.f;  // /log2(256)
        float gmax = -FLT_MAX;
        for (int i = 0; i < IMG_B; ++i) gmax = fmaxf(gmax, decf(mm[i * 2 + 1]));
        float sc = (gmax > 1.f) ? (1.f / 16383.f) : 1.f;
        double N = (double)NPIX;
        double S = mom[0], S2 = mom[1], LS = mom[2], LS2 = mom[3];
        double sc2 = (double)sc * (double)sc;
        float var  = (float)((S2  - S  * S  / N) / (N - 1.0) * sc2);
        float lvar = (float)((LS2 - LS * LS / N) / (N - 1.0) * sc2);
        float mn = decf(mm[b * 2 + 0]) * sc;
        float mx = decf(mm[b * 2 + 1]) * sc;
        float* fo = out + 16 + 48 + b * 5;  // feats region
        fo[0] = var; fo[1] = mn; fo[2] = mx; fo[3] = ent; fo[4] = lvar;
        float* fw = featsw + b * 5;
        fw[0] = var; fw[1] = mn; fw[2] = mx; fw[3] = ent; fw[4] = lvar;
    }
}

__global__ __launch_bounds__(64) void k_pass4(const float* __restrict__ feats,
                                              const float* __restrict__ W1, const float* __restrict__ b1,
                                              const float* __restrict__ W2, const float* __restrict__ b2,
                                              const float* __restrict__ W3, const float* __restrict__ b3,
                                              float* __restrict__ out) {
    int t = threadIdx.x;
    int b = blockIdx.x;           // one image per block
    __shared__ float f[5], h1[64], h2[64], lg[3];
    if (t < 5) f[t] = feats[b * 5 + t];
    __syncthreads();
    float a = b1[t];
    #pragma unroll
    for (int k = 0; k < 5; ++k) a += W1[t * 5 + k] * f[k];
    h1[t] = fmaxf(a, 0.f);
    __syncthreads();
    float a2 = b2[t];
    #pragma unroll
    for (int k = 0; k < 64; ++k) a2 += W2[t * 64 + k] * h1[k];
    h2[t] = fmaxf(a2, 0.f);
    __syncthreads();
    if (t < 3) {
        float a3 = b3[t];
        #pragma unroll
        for (int k = 0; k < 64; ++k) a3 += W3[t * 64 + k] * h2[k];
        lg[t] = a3;
    }
    __syncthreads();
    if (t == 0) {
        float m = fmaxf(lg[0], fmaxf(lg[1], lg[2]));
        float e0 = expf(lg[0] - m), e1 = expf(lg[1] - m), e2 = expf(lg[2] - m);
        float inv = 1.f / (e0 + e1 + e2);
        float p0 = e0 * inv, p1 = e1 * inv, p2 = e2 * inv;
        out[16 + b * 3 + 0] = p0;
        out[16 + b * 3 + 1] = p1;
        out[16 + b * 3 + 2] = p2;
        int cid = 0; float bm = p0;
        if (p1 > bm) { bm = p1; cid = 1; }
        if (p2 > bm) { bm = p2; cid = 2; }
        out[b] = (float)cid;
    }
}

extern "C" void kernel_launch(void* const* d_in, const int* in_sizes, int n_in,
                              void* d_out, int out_size, void* d_ws, size_t ws_size,
                              hipStream_t stream) {
    const float* img = (const float*)d_in[0];
    const float* W1  = (const float*)d_in[1];
    const float* b1  = (const float*)d_in[2];
    const float* W2  = (const float*)d_in[3];
    const float* b2  = (const float*)d_in[4];
    const float* W3  = (const float*)d_in[5];
    const float* b3  = (const float*)d_in[6];
    float* out = (float*)d_out;

    char* ws = (char*)d_ws;
    double*             partials = (double*)ws;                    // 1024*4 doubles = 32 KB
    unsigned*           mm       = (unsigned*)(ws + 32768);        // 16*2 uints
    unsigned long long* hist64   = (unsigned long long*)(ws + 32896);  // 16*256 u64 = 32 KB
    float*              featsw   = (float*)(ws + 65664);           // 16*5 floats

    k_init <<<16, 256, 0, stream>>>(mm, hist64);
    k_pass1<<<IMG_B * BLOCKS_PER_IMG_P1, T1, 0, stream>>>(img, partials, mm);
    k_pass2<<<IMG_B * BPI2, 256, 0, stream>>>(img, mm, hist64);
    k_pass3<<<IMG_B, 256, 0, stream>>>(hist64, partials, mm, featsw, out);
    k_pass4<<<IMG_B, 64, 0, stream>>>(featsw, W1, b1, W2, b2, W3, b3, out);
}